// Round 2
// baseline (4221.359 us; speedup 1.0000x reference)
//
#include <hip/hip_runtime.h>
#include <math.h>

namespace {
constexpr int B  = 4;
constexpr int L  = 2048;
constexpr int D  = 512;
constexpr int NH = 8;
constexpr int DH = 64;
constexpr int TM = 16;   // query rows per block
constexpr int TN = 64;   // key cols per tile
constexpr int LDP = 68;  // padded LDS row stride in floats (68%4==0 -> float4 aligned)
}

// Y[b,h,l,d] = sum_k X[b*L+l, k] * W[k, h*DH+d]   (einsum 'bld,de->ble' + head split)
__global__ __launch_bounds__(256)
void proj_kernel(const float* __restrict__ X, const float* __restrict__ W,
                 float* __restrict__ Y) {
    __shared__ float As[64][17];
    __shared__ float Bs[16][65];
    const int bx = blockIdx.x;   // 8 col tiles  (N=512)
    const int by = blockIdx.y;   // 128 row tiles (M=8192)
    const int t  = threadIdx.x;
    const int tx = t & 15, ty = t >> 4;
    float acc[4][4] = {};

    for (int k0 = 0; k0 < D; k0 += 16) {
#pragma unroll
        for (int i = 0; i < 4; ++i) {
            int idx = t * 4 + i;                       // 0..1023
            int ar = idx >> 4, ak = idx & 15;          // A: 64 rows x 16 k
            As[ar][ak] = X[(size_t)(by * 64 + ar) * D + k0 + ak];
            int bk = idx >> 6, bc = idx & 63;          // B: 16 k x 64 cols
            Bs[bk][bc] = W[(size_t)(k0 + bk) * D + bx * 64 + bc];
        }
        __syncthreads();
#pragma unroll
        for (int kk = 0; kk < 16; ++kk) {
            float a[4], b[4];
#pragma unroll
            for (int i = 0; i < 4; ++i) a[i] = As[ty * 4 + i][kk];
#pragma unroll
            for (int j = 0; j < 4; ++j) b[j] = Bs[kk][tx * 4 + j];
#pragma unroll
            for (int i = 0; i < 4; ++i)
#pragma unroll
                for (int j = 0; j < 4; ++j) acc[i][j] += a[i] * b[j];
        }
        __syncthreads();
    }
    // scatter to [B, NH, L, DH]
#pragma unroll
    for (int i = 0; i < 4; ++i) {
        int m  = by * 64 + ty * 4 + i;
        int bb = m >> 11;        // / 2048
        int l  = m & 2047;
#pragma unroll
        for (int j = 0; j < 4; ++j) {
            int n = bx * 64 + tx * 4 + j;
            int h = n >> 6, d = n & 63;
            Y[((size_t)(bb * NH + h) * L + l) * DH + d] = acc[i][j];
        }
    }
}

// Flash-style attention with relative-position skew folded in analytically:
//   rel = c - l;  rel<=0 : Srel = q[l]   . E[rel+L-1]
//                 rel==1 : Srel = 0
//                 rel>=2 : Srel = q[l+1] . E[rel-2]
// (verified against the reference pad/reshape/slice algebra)
// softmax over full row (no mask!), divided by sqrt(dh)=8 AFTER softmax.
__global__ __launch_bounds__(256)
void attn_kernel(const float* __restrict__ qh, const float* __restrict__ kh,
                 const float* __restrict__ vh, const float* __restrict__ Ef,
                 float* __restrict__ out) {
    const int l0 = blockIdx.x * TM;
    const int h  = blockIdx.y;
    const int bb = blockIdx.z;
    const size_t base = (size_t)(bb * NH + h) * L * DH;
    const float* Q = qh + base;
    const float* K = kh + base;
    const float* V = vh + base;

    __shared__ float Qs[(TM + 1) * LDP];
    __shared__ float Ks[TN * LDP];
    __shared__ float Vs[TN * LDP];
    __shared__ float P[TM][TN];

    const int t = threadIdx.x;
    const int r = t >> 4;   // query row within tile (0..15)
    const int g = t & 15;   // lane within 16-thread row group

    // stage Q tile: TM+1 rows (row l0+TM needed for rel>=2 of last row)
    for (int i = t; i < (TM + 1) * (DH / 4); i += 256) {
        int row = i >> 4, q4 = i & 15;
        int gl = l0 + row;
        float4 v4 = make_float4(0.f, 0.f, 0.f, 0.f);
        if (gl < L) v4 = ((const float4*)(Q + (size_t)gl * DH))[q4];
        ((float4*)(Qs + row * LDP))[q4] = v4;
    }

    float m_r = -1e30f, s_r = 0.f;
    float a0 = 0.f, a1 = 0.f, a2 = 0.f, a3 = 0.f;

    for (int c0 = 0; c0 < L; c0 += TN) {
        __syncthreads();   // prev PV done (and Q staging on first iter)
        // stage K/V tiles: 64 rows x 16 float4 each
        for (int i = t; i < TN * (DH / 4); i += 256) {
            int row = i >> 4, q4 = i & 15;
            ((float4*)(Ks + row * LDP))[q4] = ((const float4*)(K + (size_t)(c0 + row) * DH))[q4];
            ((float4*)(Vs + row * LDP))[q4] = ((const float4*)(V + (size_t)(c0 + row) * DH))[q4];
        }
        __syncthreads();

        // S: thread (r,g) computes cols c = g + 16*i
        float sv[4];
        float tmax = -1e30f;
#pragma unroll
        for (int i = 0; i < 4; ++i) {
            const int c   = g + 16 * i;
            const int rel = (c0 + c) - (l0 + r);
            const int lrow = (rel >= 2) ? (r + 1) : r;
            int erow = (rel <= 0) ? (rel + L - 1) : (rel - 2);
            const bool hasr = (rel != 1);
            if (!hasr) erow = 0;
            const float4* q1 = (const float4*)(Qs + r * LDP);
            const float4* q2 = (const float4*)(Qs + lrow * LDP);
            const float4* kp = (const float4*)(Ks + c * LDP);
            const float4* ep = (const float4*)(Ef + (size_t)erow * DH);
            float qk = 0.f, sr = 0.f;
#pragma unroll
            for (int kk = 0; kk < 16; ++kk) {
                float4 qa = q1[kk], ka = kp[kk];
                qk += qa.x * ka.x + qa.y * ka.y + qa.z * ka.z + qa.w * ka.w;
                float4 qb = q2[kk], ea = ep[kk];
                sr += qb.x * ea.x + qb.y * ea.y + qb.z * ea.z + qb.w * ea.w;
            }
            float s = qk + (hasr ? sr : 0.f);
            sv[i] = s;
            tmax = fmaxf(tmax, s);
        }
        // row-group reductions (16 consecutive lanes within one wave)
#pragma unroll
        for (int mask = 1; mask < 16; mask <<= 1)
            tmax = fmaxf(tmax, __shfl_xor(tmax, mask, 16));
        const float new_m = fmaxf(m_r, tmax);
        const float alpha = __expf(m_r - new_m);
        float psum = 0.f;
#pragma unroll
        for (int i = 0; i < 4; ++i) {
            const int c = g + 16 * i;
            float p = __expf(sv[i] - new_m);
            P[r][c] = p;
            psum += p;
        }
#pragma unroll
        for (int mask = 1; mask < 16; mask <<= 1)
            psum += __shfl_xor(psum, mask, 16);
        s_r = s_r * alpha + psum;
        m_r = new_m;
        __syncthreads();   // P visible

        // PV: thread (r,g) owns out dims d = g*4 .. g*4+3 of row r
        a0 *= alpha; a1 *= alpha; a2 *= alpha; a3 *= alpha;
#pragma unroll 8
        for (int c = 0; c < TN; ++c) {
            const float p = P[r][c];                       // LDS broadcast
            const float4 vv = *(const float4*)(Vs + c * LDP + g * 4);
            a0 += p * vv.x; a1 += p * vv.y; a2 += p * vv.z; a3 += p * vv.w;
        }
    }

    const float inv = 1.0f / (s_r * 8.0f);   // /sqrt(dh) applied after softmax
    const int gl = l0 + r;
    float* o = out + ((size_t)(bb * L + gl)) * D + h * DH + g * 4;
    *(float4*)o = make_float4(a0 * inv, a1 * inv, a2 * inv, a3 * inv);
}

extern "C" void kernel_launch(void* const* d_in, const int* in_sizes, int n_in,
                              void* d_out, int out_size, void* d_ws, size_t ws_size,
                              hipStream_t stream) {
    const float* q  = (const float*)d_in[0];
    const float* k  = (const float*)d_in[1];
    const float* v  = (const float*)d_in[2];
    const float* Wq = (const float*)d_in[3];
    const float* Wk = (const float*)d_in[4];
    const float* Wv = (const float*)d_in[5];
    const float* E  = (const float*)d_in[6];
    float* out = (float*)d_out;

    // ws layout: qh | kh | vh (fp32 [B,NH,L,DH] each, 16 MB) = 48 MB
    float* qh = (float*)d_ws;
    float* kh = qh + (size_t)B * NH * L * DH;
    float* vh = kh + (size_t)B * NH * L * DH;

    dim3 gproj(8, 128);
    proj_kernel<<<gproj, 256, 0, stream>>>(q, Wq, qh);
    proj_kernel<<<gproj, 256, 0, stream>>>(k, Wk, kh);
    proj_kernel<<<gproj, 256, 0, stream>>>(v, Wv, vh);

    dim3 gattn(L / TM, NH, B);
    attn_kernel<<<gattn, 256, 0, stream>>>(qh, kh, vh, E, out);
}

// Round 3
// 862.324 us; speedup vs baseline: 4.8953x; 4.8953x over previous
//
#include <hip/hip_runtime.h>
#include <hip/hip_bf16.h>
#include <math.h>

typedef __hip_bfloat16 bf16;
typedef __attribute__((ext_vector_type(8))) short bf16x8;
typedef __attribute__((ext_vector_type(4))) float f32x4;

namespace {
constexpr int B = 4, L = 2048, D = 512, NH = 8, DH = 64;
}

__device__ __forceinline__ short f2bf(float x) {
    bf16 h = __float2bfloat16(x);
    return *reinterpret_cast<short*>(&h);
}
__device__ __forceinline__ float bf2f(short s) {
    bf16 h; *reinterpret_cast<short*>(&h) = s;
    return __bfloat162float(h);
}

__global__ void e_cast_kernel(const float* __restrict__ E, bf16* __restrict__ Eb) {
    int i = blockIdx.x * 256 + threadIdx.x;
    if (i < L * DH) Eb[i] = __float2bfloat16(E[i]);
}

// Y[b,h,l,d] = sum_k X[b*L+l, k] * W[k, h*DH+d]
// mode 0: write split hi/lo bf16 planes [b,h,l,dh]
// mode 1: write single bf16 TRANSPOSED plane [b,h,dh,l]  (for V)
__global__ __launch_bounds__(256)
void proj_kernel(const float* __restrict__ X, const float* __restrict__ W,
                 bf16* __restrict__ Yhi, bf16* __restrict__ Ylo, int mode) {
    __shared__ float As[64][17];
    __shared__ float Bs[16][65];
    const int bx = blockIdx.x;   // 8 col tiles  (N=512)
    const int by = blockIdx.y;   // 128 row tiles (M=8192)
    const int t  = threadIdx.x;
    const int tx = t & 15, ty = t >> 4;
    float acc[4][4] = {};

    for (int k0 = 0; k0 < D; k0 += 16) {
#pragma unroll
        for (int i = 0; i < 4; ++i) {
            int idx = t * 4 + i;
            int ar = idx >> 4, ak = idx & 15;
            As[ar][ak] = X[(size_t)(by * 64 + ar) * D + k0 + ak];
            int bk = idx >> 6, bc = idx & 63;
            Bs[bk][bc] = W[(size_t)(k0 + bk) * D + bx * 64 + bc];
        }
        __syncthreads();
#pragma unroll
        for (int kk = 0; kk < 16; ++kk) {
            float a[4], b[4];
#pragma unroll
            for (int i = 0; i < 4; ++i) a[i] = As[ty * 4 + i][kk];
#pragma unroll
            for (int j = 0; j < 4; ++j) b[j] = Bs[kk][tx * 4 + j];
#pragma unroll
            for (int i = 0; i < 4; ++i)
#pragma unroll
                for (int j = 0; j < 4; ++j) acc[i][j] += a[i] * b[j];
        }
        __syncthreads();
    }
#pragma unroll
    for (int i = 0; i < 4; ++i) {
        int m  = by * 64 + ty * 4 + i;
        int bb = m >> 11;
        int l  = m & 2047;
#pragma unroll
        for (int j = 0; j < 4; ++j) {
            int n = bx * 64 + tx * 4 + j;
            int h = n >> 6, d = n & 63;
            float a = acc[i][j];
            if (mode == 0) {
                bf16 hi = __float2bfloat16(a);
                float lo = a - __bfloat162float(hi);
                size_t idx = ((size_t)(bb * NH + h) * L + l) * DH + d;
                Yhi[idx] = hi;
                Ylo[idx] = __float2bfloat16(lo);
            } else {
                size_t idx = ((size_t)(bb * NH + h) * DH + d) * L + l;
                Yhi[idx] = __float2bfloat16(a);
            }
        }
    }
}

// Flash attention, MFMA 16x16x32 bf16. One wave (64 threads) per block,
// 16 query rows per wave. Skew folded analytically:
//   rel = c-l; rel<=0: q[l].E[rel+L-1]; rel==1: 0; rel>=2: q[l+1].E[rel-2]
// Both cases map to G[r][jj], jj = cc-r+15, with jbaseA=d0+L-16 / jbaseB=d0-17.
// Softmax over unscaled logits; /8 applied after softmax.
__global__ __launch_bounds__(64)
void attn_kernel(const bf16* __restrict__ Qhi, const bf16* __restrict__ Qlo,
                 const bf16* __restrict__ Khi, const bf16* __restrict__ Klo,
                 const bf16* __restrict__ Vt,  const bf16* __restrict__ Eb,
                 float* __restrict__ out) {
    __shared__ __align__(16) short Pbuf[16 * 72];  // stride 72 shorts = 144B (16B-aligned rows)
    __shared__ __align__(16) short Gbuf[16 * 84];  // stride 84: quad bank shift 8 -> conflict-free

    const int l0w = blockIdx.x * 16;
    const int h = blockIdx.y, bb = blockIdx.z;
    const int lane = threadIdx.x;
    const int quad = lane >> 4, col = lane & 15;

    const size_t head = (size_t)(bb * NH + h) * (size_t)(L * DH);
    const bf16* qh = Qhi + head;
    const bf16* ql = Qlo + head;
    const bf16* kh = Khi + head;
    const bf16* kl = Klo + head;
    const bf16* vt = Vt + head;   // [dh][l]

    // Q A-fragments, loaded once: A[m=col][k=quad*8+j+32*ks]
    bf16x8 qhiF[2], qloF[2], qhiS[2];
    {
        const int m  = l0w + col;
        const int mS = min(m + 1, L - 1);   // shifted rows for rel>=2 (row L never used)
#pragma unroll
        for (int ks = 0; ks < 2; ++ks) {
            const int off = quad * 8 + ks * 32;
            qhiF[ks] = *(const bf16x8*)(qh + (size_t)m  * DH + off);
            qloF[ks] = *(const bf16x8*)(ql + (size_t)m  * DH + off);
            qhiS[ks] = *(const bf16x8*)(qh + (size_t)mS * DH + off);
        }
    }

    f32x4 O[4];
#pragma unroll
    for (int i = 0; i < 4; ++i) O[i] = (f32x4){0.f, 0.f, 0.f, 0.f};
    float mrow[4] = {-1e30f, -1e30f, -1e30f, -1e30f};
    float srow[4] = {0.f, 0.f, 0.f, 0.f};

    for (int c0 = 0; c0 < L; c0 += 64) {
        const int d0 = c0 - l0w;

        // ---- S = Q K^T, split-bf16 x3 (hi*hi + lo*hi + hi*lo) ----
        f32x4 S[4];
#pragma unroll
        for (int ns = 0; ns < 4; ++ns) {
            S[ns] = (f32x4){0.f, 0.f, 0.f, 0.f};
            const size_t rowb = (size_t)(c0 + ns * 16 + col) * DH + quad * 8;
#pragma unroll
            for (int ks = 0; ks < 2; ++ks) {
                bf16x8 bh = *(const bf16x8*)(kh + rowb + ks * 32);
                bf16x8 bl = *(const bf16x8*)(kl + rowb + ks * 32);
                S[ns] = __builtin_amdgcn_mfma_f32_16x16x32_bf16(qhiF[ks], bh, S[ns], 0, 0, 0);
                S[ns] = __builtin_amdgcn_mfma_f32_16x16x32_bf16(qloF[ks], bh, S[ns], 0, 0, 0);
                S[ns] = __builtin_amdgcn_mfma_f32_16x16x32_bf16(qhiF[ks], bl, S[ns], 0, 0, 0);
            }
        }

        // ---- Srel via G rectangles (16x80), single bf16 ----
        const bool doA = (d0 <= 15);    // some rel <= 0 exists
        const bool doB = (d0 >= -61);   // some rel >= 2 exists
#pragma unroll 1
        for (int pass = 0; pass < 2; ++pass) {
            if ((pass == 0 && !doA) || (pass == 1 && !doB)) continue;
            const int jbase = (pass == 0) ? (d0 + L - 16) : (d0 - 17);
#pragma unroll
            for (int g = 0; g < 5; ++g) {
                int er = jbase + g * 16 + col;
                er = min(max(er, 0), L - 1);      // clamp; OOB entries unused
                f32x4 G = (f32x4){0.f, 0.f, 0.f, 0.f};
                const size_t ebase = (size_t)er * DH + quad * 8;
#pragma unroll
                for (int ks = 0; ks < 2; ++ks) {
                    bf16x8 e8 = *(const bf16x8*)(Eb + ebase + ks * 32);
                    G = __builtin_amdgcn_mfma_f32_16x16x32_bf16(
                            (pass == 0) ? qhiF[ks] : qhiS[ks], e8, G, 0, 0, 0);
                }
#pragma unroll
                for (int reg = 0; reg < 4; ++reg)
                    Gbuf[(quad * 4 + reg) * 84 + g * 16 + col] = f2bf(G[reg]);
            }
            __syncthreads();   // single-wave block: cheap; orders Gbuf
#pragma unroll
            for (int ns = 0; ns < 4; ++ns) {
#pragma unroll
                for (int reg = 0; reg < 4; ++reg) {
                    const int r  = quad * 4 + reg;
                    const int cc = ns * 16 + col;
                    const int rel = d0 + cc - r;
                    const bool use = (pass == 0) ? (rel <= 0) : (rel >= 2);
                    if (use) S[ns][reg] += bf2f(Gbuf[r * 84 + cc - r + 15]);
                }
            }
            __syncthreads();
        }

        // ---- online softmax (row = quad*4+reg; 16-lane row groups) ----
#pragma unroll
        for (int reg = 0; reg < 4; ++reg) {
            float t = fmaxf(fmaxf(S[0][reg], S[1][reg]), fmaxf(S[2][reg], S[3][reg]));
#pragma unroll
            for (int msk = 1; msk < 16; msk <<= 1)
                t = fmaxf(t, __shfl_xor(t, msk, 16));
            const float mnew  = fmaxf(mrow[reg], t);
            const float alpha = __expf(mrow[reg] - mnew);
            float p[4], ps = 0.f;
#pragma unroll
            for (int ns = 0; ns < 4; ++ns) { p[ns] = __expf(S[ns][reg] - mnew); ps += p[ns]; }
#pragma unroll
            for (int msk = 1; msk < 16; msk <<= 1)
                ps += __shfl_xor(ps, msk, 16);
            srow[reg] = srow[reg] * alpha + ps;
            mrow[reg] = mnew;
            const int r = quad * 4 + reg;
#pragma unroll
            for (int ns = 0; ns < 4; ++ns) {
                O[ns][reg] *= alpha;
                Pbuf[r * 72 + ns * 16 + col] = f2bf(p[ns]);
            }
        }
        __syncthreads();   // Pbuf visible

        // ---- O += P V : A-frag of P from LDS, B-frag of V^T from global ----
        bf16x8 pA[2];
        pA[0] = *(const bf16x8*)(&Pbuf[col * 72 + quad * 8]);
        pA[1] = *(const bf16x8*)(&Pbuf[col * 72 + 32 + quad * 8]);
#pragma unroll
        for (int ns = 0; ns < 4; ++ns) {
            const size_t vb = (size_t)(ns * 16 + col) * L + c0 + quad * 8;
#pragma unroll
            for (int ks = 0; ks < 2; ++ks) {
                bf16x8 v8 = *(const bf16x8*)(vt + vb + ks * 32);
                O[ns] = __builtin_amdgcn_mfma_f32_16x16x32_bf16(pA[ks], v8, O[ns], 0, 0, 0);
            }
        }
        __syncthreads();   // Pbuf reads done before next iter overwrites
    }

    // ---- epilogue: /(s*8), write fp32 out[b][l][h*64+dh] ----
#pragma unroll
    for (int reg = 0; reg < 4; ++reg) {
        const int l = l0w + quad * 4 + reg;
        const float inv = 1.0f / (srow[reg] * 8.0f);
        float* o = out + ((size_t)bb * L + l) * D + h * DH;
#pragma unroll
        for (int ns = 0; ns < 4; ++ns)
            o[ns * 16 + col] = O[ns][reg] * inv;
    }
}

extern "C" void kernel_launch(void* const* d_in, const int* in_sizes, int n_in,
                              void* d_out, int out_size, void* d_ws, size_t ws_size,
                              hipStream_t stream) {
    const float* q  = (const float*)d_in[0];
    const float* k  = (const float*)d_in[1];
    const float* v  = (const float*)d_in[2];
    const float* Wq = (const float*)d_in[3];
    const float* Wk = (const float*)d_in[4];
    const float* Wv = (const float*)d_in[5];
    const float* E  = (const float*)d_in[6];
    float* out = (float*)d_out;

    // ws: 5 bf16 planes of B*NH*L*DH = 4M elements (8 MB) + Eb (256 KB) = ~40.3 MB
    const size_t plane = (size_t)B * NH * L * DH;
    bf16* Qhi = (bf16*)d_ws;
    bf16* Qlo = Qhi + plane;
    bf16* Khi = Qlo + plane;
    bf16* Klo = Khi + plane;
    bf16* Vt  = Klo + plane;
    bf16* Eb  = Vt + plane;

    dim3 gproj(8, 128);
    proj_kernel<<<gproj, 256, 0, stream>>>(q, Wq, Qhi, Qlo, 0);
    proj_kernel<<<gproj, 256, 0, stream>>>(k, Wk, Khi, Klo, 0);
    proj_kernel<<<gproj, 256, 0, stream>>>(v, Wv, Vt, nullptr, 1);
    e_cast_kernel<<<(L * DH + 255) / 256, 256, 0, stream>>>(E, Eb);

    dim3 gattn(L / 16, NH, B);
    attn_kernel<<<gattn, 64, 0, stream>>>(Qhi, Qlo, Khi, Klo, Vt, Eb, out);
}

// Round 4
// 477.093 us; speedup vs baseline: 8.8481x; 1.8075x over previous
//
#include <hip/hip_runtime.h>
#include <hip/hip_bf16.h>
#include <math.h>

typedef __hip_bfloat16 bf16;
typedef __attribute__((ext_vector_type(8))) short bf16x8;
typedef __attribute__((ext_vector_type(4))) short s16x4;
typedef __attribute__((ext_vector_type(4))) float f32x4;

namespace {
constexpr int B = 4, L = 2048, D = 512, NH = 8, DH = 64;
}

__device__ __forceinline__ short f2bf(float x) {
    bf16 h = __float2bfloat16(x);
    return *reinterpret_cast<short*>(&h);
}
__device__ __forceinline__ float bf2f(short s) {
    bf16 h; *reinterpret_cast<short*>(&h) = s;
    return __bfloat162float(h);
}

__global__ void e_cast_kernel(const float* __restrict__ E, short* __restrict__ Eb) {
    int i = blockIdx.x * 256 + threadIdx.x;
    if (i < L * DH) Eb[i] = f2bf(E[i]);
}

// W[k][n] fp32 -> Wt[n][k] hi/lo bf16 (512x512)
__global__ void wt_cast_kernel(const float* __restrict__ W,
                               short* __restrict__ Whi, short* __restrict__ Wlo) {
    int idx = blockIdx.x * 256 + threadIdx.x;   // k*512+n
    int kk = idx >> 9, n = idx & 511;
    float w = W[idx];
    short h = f2bf(w);
    size_t o = (size_t)n * 512 + kk;
    Whi[o] = h;
    Wlo[o] = f2bf(w - bf2f(h));
}

// C[m][n] = sum_k X[m][k] W[k][n], M=8192 N=512 K=512, split-bf16 3-pass MFMA.
// mode 0: Yhi/Ylo planes [b,h,l,dh]; mode 1: single plane TRANSPOSED [b,h,dh,l].
__global__ __launch_bounds__(256)
void proj_gemm(const float* __restrict__ X, const short* __restrict__ Wthi,
               const short* __restrict__ Wtlo, short* __restrict__ Yhi,
               short* __restrict__ Ylo, int mode) {
    __shared__ short Ahi[128 * 36], Alo[128 * 36], Bhi[128 * 36], Blo[128 * 36];
    const int m0 = blockIdx.x * 128, n0 = blockIdx.y * 128;
    const int t = threadIdx.x, wid = t >> 6, lane = t & 63;
    const int quad = lane >> 4, col = lane & 15;
    const int mw = (wid >> 1) * 64, nw = (wid & 1) * 64;

    f32x4 acc[4][4];
#pragma unroll
    for (int i = 0; i < 4; ++i)
#pragma unroll
        for (int j = 0; j < 4; ++j) acc[i][j] = (f32x4){0.f, 0.f, 0.f, 0.f};

    float4 xa[4];
    bf16x8 wh[2], wl[2];

    auto loadG = [&](int k0) {
#pragma unroll
        for (int i = 0; i < 4; ++i) {
            int idx = t * 4 + i;
            int r = idx >> 3, c4 = idx & 7;
            xa[i] = *(const float4*)(X + (size_t)(m0 + r) * D + k0 + c4 * 4);
        }
#pragma unroll
        for (int i = 0; i < 2; ++i) {
            int idx = t * 2 + i;
            int n = idx >> 2, c8 = idx & 3;
            wh[i] = *(const bf16x8*)(Wthi + (size_t)(n0 + n) * D + k0 + c8 * 8);
            wl[i] = *(const bf16x8*)(Wtlo + (size_t)(n0 + n) * D + k0 + c8 * 8);
        }
    };
    auto storeL = [&]() {
#pragma unroll
        for (int i = 0; i < 4; ++i) {
            int idx = t * 4 + i;
            int r = idx >> 3, c4 = idx & 7;
            float xs[4] = {xa[i].x, xa[i].y, xa[i].z, xa[i].w};
            s16x4 hi, lo;
#pragma unroll
            for (int j = 0; j < 4; ++j) {
                short h = f2bf(xs[j]);
                hi[j] = h;
                lo[j] = f2bf(xs[j] - bf2f(h));
            }
            *(s16x4*)(Ahi + r * 36 + c4 * 4) = hi;
            *(s16x4*)(Alo + r * 36 + c4 * 4) = lo;
        }
#pragma unroll
        for (int i = 0; i < 2; ++i) {
            int idx = t * 2 + i;
            int n = idx >> 2, c8 = idx & 3;
            *(bf16x8*)(Bhi + n * 36 + c8 * 8) = wh[i];
            *(bf16x8*)(Blo + n * 36 + c8 * 8) = wl[i];
        }
    };

    loadG(0);
    storeL();
    __syncthreads();
    for (int k0 = 0; k0 < D; k0 += 32) {
        if (k0 + 32 < D) loadG(k0 + 32);
        bf16x8 ah[4], al[4], bh[4], bl[4];
#pragma unroll
        for (int mt = 0; mt < 4; ++mt) {
            ah[mt] = *(const bf16x8*)(Ahi + (mw + mt * 16 + col) * 36 + quad * 8);
            al[mt] = *(const bf16x8*)(Alo + (mw + mt * 16 + col) * 36 + quad * 8);
        }
#pragma unroll
        for (int nt = 0; nt < 4; ++nt) {
            bh[nt] = *(const bf16x8*)(Bhi + (nw + nt * 16 + col) * 36 + quad * 8);
            bl[nt] = *(const bf16x8*)(Blo + (nw + nt * 16 + col) * 36 + quad * 8);
        }
#pragma unroll
        for (int mt = 0; mt < 4; ++mt)
#pragma unroll
            for (int nt = 0; nt < 4; ++nt) {
                acc[mt][nt] = __builtin_amdgcn_mfma_f32_16x16x32_bf16(ah[mt], bh[nt], acc[mt][nt], 0, 0, 0);
                acc[mt][nt] = __builtin_amdgcn_mfma_f32_16x16x32_bf16(al[mt], bh[nt], acc[mt][nt], 0, 0, 0);
                acc[mt][nt] = __builtin_amdgcn_mfma_f32_16x16x32_bf16(ah[mt], bl[nt], acc[mt][nt], 0, 0, 0);
            }
        __syncthreads();
        if (k0 + 32 < D) {
            storeL();
            __syncthreads();
        }
    }

#pragma unroll
    for (int mt = 0; mt < 4; ++mt)
#pragma unroll
        for (int nt = 0; nt < 4; ++nt)
#pragma unroll
            for (int reg = 0; reg < 4; ++reg) {
                int m = m0 + mw + mt * 16 + quad * 4 + reg;
                int n = n0 + nw + nt * 16 + col;
                int bb = m >> 11, l = m & 2047, h = n >> 6, d = n & 63;
                float a = acc[mt][nt][reg];
                if (mode == 0) {
                    short hi = f2bf(a);
                    size_t idx = ((size_t)(bb * NH + h) * L + l) * DH + d;
                    Yhi[idx] = hi;
                    Ylo[idx] = f2bf(a - bf2f(hi));
                } else {
                    size_t idx = ((size_t)(bb * NH + h) * DH + d) * L + l;
                    Yhi[idx] = f2bf(a);
                }
            }
}

// Flash attention, 4 waves/block (64 q rows), K/V LDS-staged, shuffle skew-scatter.
//   rel = c-l; rel<=0: q[l].E[rel+L-1]; rel==1: 0; rel>=2: q[l+1].E[rel-2]
// Both map to G[r][cc-r+15] with jbaseA=d0+L-16 / jbaseB=d0-17.
// Softmax over unscaled logits; /8 applied after softmax.
__global__ __launch_bounds__(256)
void attn_kernel(const short* __restrict__ Qhi, const short* __restrict__ Qlo,
                 const short* __restrict__ Khi, const short* __restrict__ Klo,
                 const short* __restrict__ Vt,  const short* __restrict__ Eb,
                 float* __restrict__ out) {
    __shared__ short KhiS[64 * 72], KloS[64 * 72], VtS[64 * 72];
    __shared__ short Pbuf[4][16 * 72];

    const int t = threadIdx.x, wid = t >> 6, lane = t & 63;
    const int quad = lane >> 4, col = lane & 15;
    const int l0w = blockIdx.x * 64 + wid * 16;
    const int h = blockIdx.y, bb = blockIdx.z;
    const size_t head = (size_t)(bb * NH + h) * (size_t)(L * DH);
    const short* qh = Qhi + head;
    const short* ql = Qlo + head;
    const short* kh = Khi + head;
    const short* kl = Klo + head;
    const short* vt = Vt + head;    // [dh][L]
    short* Pw = Pbuf[wid];

    bf16x8 qhiF[2], qloF[2], qhiS_[2];
    {
        const int m = l0w + col;
        const int mS = min(m + 1, L - 1);
#pragma unroll
        for (int ks = 0; ks < 2; ++ks) {
            const int off = quad * 8 + ks * 32;
            qhiF[ks]  = *(const bf16x8*)(qh + (size_t)m * DH + off);
            qloF[ks]  = *(const bf16x8*)(ql + (size_t)m * DH + off);
            qhiS_[ks] = *(const bf16x8*)(qh + (size_t)mS * DH + off);
        }
    }

    f32x4 O[4];
#pragma unroll
    for (int i = 0; i < 4; ++i) O[i] = (f32x4){0.f, 0.f, 0.f, 0.f};
    float mrow[4] = {-1e30f, -1e30f, -1e30f, -1e30f};
    float srow[4] = {0.f, 0.f, 0.f, 0.f};

    for (int c0 = 0; c0 < L; c0 += 64) {
        __syncthreads();   // all waves done with prev tiles
#pragma unroll
        for (int i = 0; i < 2; ++i) {
            int idx = t * 2 + i;
            int row = idx >> 3, ch = idx & 7;
            *(bf16x8*)(KhiS + row * 72 + ch * 8) = *(const bf16x8*)(kh + (size_t)(c0 + row) * DH + ch * 8);
            *(bf16x8*)(KloS + row * 72 + ch * 8) = *(const bf16x8*)(kl + (size_t)(c0 + row) * DH + ch * 8);
            *(bf16x8*)(VtS  + row * 72 + ch * 8) = *(const bf16x8*)(vt + (size_t)row * L + c0 + ch * 8);
        }
        __syncthreads();

        const int d0 = c0 - l0w;

        // ---- S = Q K^T (split-bf16 x3) from LDS ----
        f32x4 S[4];
#pragma unroll
        for (int ns = 0; ns < 4; ++ns) {
            S[ns] = (f32x4){0.f, 0.f, 0.f, 0.f};
#pragma unroll
            for (int ks = 0; ks < 2; ++ks) {
                bf16x8 bh = *(const bf16x8*)(KhiS + (ns * 16 + col) * 72 + quad * 8 + ks * 32);
                bf16x8 bl = *(const bf16x8*)(KloS + (ns * 16 + col) * 72 + quad * 8 + ks * 32);
                S[ns] = __builtin_amdgcn_mfma_f32_16x16x32_bf16(qhiF[ks], bh, S[ns], 0, 0, 0);
                S[ns] = __builtin_amdgcn_mfma_f32_16x16x32_bf16(qloF[ks], bh, S[ns], 0, 0, 0);
                S[ns] = __builtin_amdgcn_mfma_f32_16x16x32_bf16(qhiF[ks], bl, S[ns], 0, 0, 0);
            }
        }

        // ---- Srel: G = Q(.E-window)^T, scatter via intra-quad shuffles ----
        const bool doA = (d0 <= 15);
        const bool doB = (d0 >= -61);
#pragma unroll 1
        for (int pass = 0; pass < 2; ++pass) {
            if ((pass == 0 && !doA) || (pass == 1 && !doB)) continue;
            const int jbase = (pass == 0) ? (d0 + L - 16) : (d0 - 17);
            f32x4 G[5];
#pragma unroll
            for (int g = 0; g < 5; ++g) {
                int er = min(max(jbase + g * 16 + col, 0), L - 1);
                G[g] = (f32x4){0.f, 0.f, 0.f, 0.f};
                const size_t eb = (size_t)er * DH + quad * 8;
#pragma unroll
                for (int ks = 0; ks < 2; ++ks) {
                    bf16x8 e8 = *(const bf16x8*)(Eb + eb + ks * 32);
                    G[g] = __builtin_amdgcn_mfma_f32_16x16x32_bf16(
                               (pass == 0) ? qhiF[ks] : qhiS_[ks], e8, G[g], 0, 0, 0);
                }
            }
#pragma unroll
            for (int reg = 0; reg < 4; ++reg) {
                const int r  = quad * 4 + reg;
                const int jj = col - r + 15;            // [0,30]
                const int src = quad * 16 + (jj & 15);  // same quad holds row r
#pragma unroll
                for (int ns = 0; ns < 4; ++ns) {
                    float v0 = __shfl(G[ns][reg], src, 64);
                    float v1 = __shfl(G[ns + 1][reg], src, 64);
                    float val = (jj < 16) ? v0 : v1;
                    const int rel = d0 + ns * 16 + col - r;
                    const bool use = (pass == 0) ? (rel <= 0) : (rel >= 2);
                    if (use) S[ns][reg] += val;
                }
            }
        }

        // ---- online softmax ----
#pragma unroll
        for (int reg = 0; reg < 4; ++reg) {
            float tm = fmaxf(fmaxf(S[0][reg], S[1][reg]), fmaxf(S[2][reg], S[3][reg]));
#pragma unroll
            for (int msk = 1; msk < 16; msk <<= 1)
                tm = fmaxf(tm, __shfl_xor(tm, msk, 16));
            const float mnew  = fmaxf(mrow[reg], tm);
            const float alpha = __expf(mrow[reg] - mnew);
            float p[4], ps = 0.f;
#pragma unroll
            for (int ns = 0; ns < 4; ++ns) { p[ns] = __expf(S[ns][reg] - mnew); ps += p[ns]; }
#pragma unroll
            for (int msk = 1; msk < 16; msk <<= 1)
                ps += __shfl_xor(ps, msk, 16);
            srow[reg] = srow[reg] * alpha + ps;
            mrow[reg] = mnew;
            const int r = quad * 4 + reg;
#pragma unroll
            for (int ns = 0; ns < 4; ++ns) {
                O[ns][reg] *= alpha;
                Pw[r * 72 + ns * 16 + col] = f2bf(p[ns]);
            }
        }
        // wave-private LDS write->read: ordered within wave via lgkmcnt

        // ---- O += P V ----
        bf16x8 pA[2];
        pA[0] = *(const bf16x8*)(Pw + col * 72 + quad * 8);
        pA[1] = *(const bf16x8*)(Pw + col * 72 + 32 + quad * 8);
#pragma unroll
        for (int ns = 0; ns < 4; ++ns) {
#pragma unroll
            for (int ks = 0; ks < 2; ++ks) {
                bf16x8 v8 = *(const bf16x8*)(VtS + (ns * 16 + col) * 72 + quad * 8 + ks * 32);
                O[ns] = __builtin_amdgcn_mfma_f32_16x16x32_bf16(pA[ks], v8, O[ns], 0, 0, 0);
            }
        }
    }

#pragma unroll
    for (int reg = 0; reg < 4; ++reg) {
        const int l = l0w + quad * 4 + reg;
        const float inv = 1.0f / (srow[reg] * 8.0f);
        float* o = out + ((size_t)bb * L + l) * D + h * DH;
#pragma unroll
        for (int ns = 0; ns < 4; ++ns)
            o[ns * 16 + col] = O[ns][reg] * inv;
    }
}

extern "C" void kernel_launch(void* const* d_in, const int* in_sizes, int n_in,
                              void* d_out, int out_size, void* d_ws, size_t ws_size,
                              hipStream_t stream) {
    const float* q  = (const float*)d_in[0];
    const float* k  = (const float*)d_in[1];
    const float* v  = (const float*)d_in[2];
    const float* Wq = (const float*)d_in[3];
    const float* Wk = (const float*)d_in[4];
    const float* Wv = (const float*)d_in[5];
    const float* E  = (const float*)d_in[6];
    float* out = (float*)d_out;

    const size_t plane = (size_t)B * NH * L * DH;   // 4M elems
    short* Qhi = (short*)d_ws;
    short* Qlo = Qhi + plane;
    short* Khi = Qlo + plane;
    short* Klo = Khi + plane;
    short* Vt  = Klo + plane;
    short* Eb  = Vt + plane;                         // 128K elems
    short* Wqh = Eb + (size_t)L * DH;
    short* Wql = Wqh + (size_t)D * D;
    short* Wkh = Wql + (size_t)D * D;
    short* Wkl = Wkh + (size_t)D * D;
    short* Wvh = Wkl + (size_t)D * D;
    short* Wvl = Wvh + (size_t)D * D;

    wt_cast_kernel<<<D * D / 256, 256, 0, stream>>>(Wq, Wqh, Wql);
    wt_cast_kernel<<<D * D / 256, 256, 0, stream>>>(Wk, Wkh, Wkl);
    wt_cast_kernel<<<D * D / 256, 256, 0, stream>>>(Wv, Wvh, Wvl);
    e_cast_kernel<<<(L * DH + 255) / 256, 256, 0, stream>>>(E, Eb);

    dim3 gproj(64, 4);
    proj_gemm<<<gproj, 256, 0, stream>>>(q, Wqh, Wql, Qhi, Qlo, 0);
    proj_gemm<<<gproj, 256, 0, stream>>>(k, Wkh, Wkl, Khi, Klo, 0);
    proj_gemm<<<gproj, 256, 0, stream>>>(v, Wvh, Wvl, Vt, nullptr, 1);

    dim3 gattn(L / 64, NH, B);
    attn_kernel<<<gattn, 256, 0, stream>>>(Qhi, Qlo, Khi, Klo, Vt, Eb, out);
}

// Round 5
// 352.558 us; speedup vs baseline: 11.9735x; 1.3532x over previous
//
#include <hip/hip_runtime.h>
#include <hip/hip_bf16.h>
#include <math.h>

typedef _Float16 f16;
typedef __attribute__((ext_vector_type(8))) _Float16 f16x8;
typedef __attribute__((ext_vector_type(4))) _Float16 f16x4;
typedef __attribute__((ext_vector_type(4))) float f32x4;

namespace {
constexpr int B = 4, L = 2048, D = 512, NH = 8, DH = 64;
}

// ---- E cast: fp32 -> fp16 (131072 elems) ----
__global__ __launch_bounds__(256)
void ecast_kernel(const float* __restrict__ E, f16* __restrict__ Ef) {
    int i4 = (blockIdx.x * 256 + threadIdx.x) * 4;
    float4 x = *(const float4*)(E + i4);
    *(f16x4*)(Ef + i4) = (f16x4){(f16)x.x, (f16)x.y, (f16)x.z, (f16)x.w};
}

// ---- W transpose+cast: W[k][n] fp32 -> Wt[sel][n][k] fp16, 64x64 tiles ----
__global__ __launch_bounds__(256)
void wtrans_kernel(const float* __restrict__ Wq, const float* __restrict__ Wk,
                   const float* __restrict__ Wv, f16* __restrict__ Wt) {
    __shared__ f16 Ws[64 * 65];
    const int sel = blockIdx.z;
    const float* W = (sel == 0) ? Wq : (sel == 1) ? Wk : Wv;
    f16* Wo = Wt + (size_t)sel * D * D;
    const int k0 = blockIdx.x * 64, n0 = blockIdx.y * 64;
    const int t = threadIdx.x;
#pragma unroll
    for (int i = 0; i < 16; ++i) {
        int idx = 256 * i + t;
        int r = idx >> 6, c = idx & 63;
        Ws[r * 65 + c] = (f16)W[(size_t)(k0 + r) * D + n0 + c];
    }
    __syncthreads();
    const int c = t >> 2, kseg = t & 3;
    f16x8 r0, r1;
#pragma unroll
    for (int j = 0; j < 8; ++j) r0[j] = Ws[(kseg * 16 + j) * 65 + c];
#pragma unroll
    for (int j = 0; j < 8; ++j) r1[j] = Ws[(kseg * 16 + 8 + j) * 65 + c];
    f16* o = Wo + (size_t)(n0 + c) * D + k0 + kseg * 16;
    *(f16x8*)o = r0;
    *(f16x8*)(o + 8) = r1;
}

// ---- fused projections: C = X(fp32) . W, fp16 MFMA single-pass ----
// grid (64, 24): bx -> 128 m-rows; by: sel = by>>3 (q/k/v), head = by&7 (64 n-cols).
// sel 0/1 -> Qf/Kf [b,h,l,dh]; sel 2 -> Vtf [b,h,dh,l] (LDS-transposed epilogue).
__global__ __launch_bounds__(256, 4)
void proj_gemm(const float* __restrict__ q, const float* __restrict__ k,
               const float* __restrict__ v, const f16* __restrict__ Wt,
               f16* __restrict__ Qf, f16* __restrict__ Kf, f16* __restrict__ Vtf) {
    __shared__ f16 As[128 * 72];
    __shared__ f16 Bs[64 * 72];
    const int bx = blockIdx.x, by = blockIdx.y;
    const int sel = by >> 3, h = by & 7;
    const int m0 = bx * 128;
    const float* X = (sel == 0) ? q : (sel == 1) ? k : v;
    const f16* Bt = Wt + (size_t)sel * D * D + (size_t)h * 64 * D;
    const int t = threadIdx.x, wid = t >> 6, lane = t & 63;
    const int quad = lane >> 4, col = lane & 15;
    const int mw = wid * 32;

    f32x4 acc[2][4];
#pragma unroll
    for (int i = 0; i < 2; ++i)
#pragma unroll
        for (int j = 0; j < 4; ++j) acc[i][j] = (f32x4){0.f, 0.f, 0.f, 0.f};

    float4 xa[8];
    f16x8 breg[2];
    auto loadG = [&](int k0) {
#pragma unroll
        for (int i = 0; i < 8; ++i) {
            int idx = 256 * i + t;
            int r = idx >> 4, c4 = idx & 15;           // 128 rows x 16 float4
            xa[i] = *(const float4*)(X + (size_t)(m0 + r) * D + k0 + c4 * 4);
        }
#pragma unroll
        for (int i = 0; i < 2; ++i) {
            int idx = 256 * i + t;
            int r = idx >> 3, ch = idx & 7;            // 64 rows x 8 chunks
            breg[i] = *(const f16x8*)(Bt + (size_t)r * D + k0 + ch * 8);
        }
    };
    auto storeL = [&]() {
#pragma unroll
        for (int i = 0; i < 8; ++i) {
            int idx = 256 * i + t;
            int r = idx >> 4, c4 = idx & 15;
            *(f16x4*)(As + r * 72 + c4 * 4) =
                (f16x4){(f16)xa[i].x, (f16)xa[i].y, (f16)xa[i].z, (f16)xa[i].w};
        }
#pragma unroll
        for (int i = 0; i < 2; ++i) {
            int idx = 256 * i + t;
            int r = idx >> 3, ch = idx & 7;
            *(f16x8*)(Bs + r * 72 + ch * 8) = breg[i];
        }
    };

    loadG(0);
    for (int k0 = 0; k0 < D; k0 += 64) {
        __syncthreads();
        storeL();
        __syncthreads();
        if (k0 + 64 < D) loadG(k0 + 64);
#pragma unroll
        for (int ks = 0; ks < 2; ++ks) {
            f16x8 af[2], bf[4];
#pragma unroll
            for (int mt = 0; mt < 2; ++mt)
                af[mt] = *(const f16x8*)(As + (mw + mt * 16 + col) * 72 + quad * 8 + ks * 32);
#pragma unroll
            for (int nt = 0; nt < 4; ++nt)
                bf[nt] = *(const f16x8*)(Bs + (nt * 16 + col) * 72 + quad * 8 + ks * 32);
#pragma unroll
            for (int mt = 0; mt < 2; ++mt)
#pragma unroll
                for (int nt = 0; nt < 4; ++nt)
                    acc[mt][nt] = __builtin_amdgcn_mfma_f32_16x16x32_f16(af[mt], bf[nt], acc[mt][nt], 0, 0, 0);
        }
    }

    if (sel < 2) {
        f16* Y = (sel == 0) ? Qf : Kf;
#pragma unroll
        for (int mt = 0; mt < 2; ++mt)
#pragma unroll
            for (int nt = 0; nt < 4; ++nt)
#pragma unroll
                for (int reg = 0; reg < 4; ++reg) {
                    int m = m0 + mw + mt * 16 + quad * 4 + reg;
                    int bb = m >> 11, l = m & 2047, d = nt * 16 + col;
                    Y[((size_t)(bb * NH + h) * L + l) * DH + d] = (f16)acc[mt][nt][reg];
                }
    } else {
        __syncthreads();                 // As frag reads done; reuse as Cs[64][136]
        f16* Cs = As;
#pragma unroll
        for (int mt = 0; mt < 2; ++mt)
#pragma unroll
            for (int nt = 0; nt < 4; ++nt)
#pragma unroll
                for (int reg = 0; reg < 4; ++reg) {
                    int d = nt * 16 + col;
                    int lc = mw + mt * 16 + quad * 4 + reg;
                    Cs[d * 136 + lc] = (f16)acc[mt][nt][reg];
                }
        __syncthreads();
        const int dd = t >> 2, seg = t & 3;
        const int bb = m0 >> 11, l0 = m0 & 2047;
        f16* Yv = Vtf + ((size_t)(bb * NH + h) * DH + dd) * L + l0 + seg * 32;
#pragma unroll
        for (int j = 0; j < 4; ++j)
            *(f16x8*)(Yv + j * 8) = *(const f16x8*)(Cs + dd * 136 + seg * 32 + j * 8);
    }
}

// ---- flash attention, fp16 MFMA, reg-prefetch K/V pipeline ----
//   rel = c-l; rel<=0: q[l].E[rel+L-1]; rel==1: 0; rel>=2: q[l+1].E[rel-2]
// G[r][jj], jj=cc-r+15, jbaseA=d0+L-16 / jbaseB=d0-17; scatter via intra-quad shfl.
// Softmax over unscaled logits; /8 after softmax.
__global__ __launch_bounds__(256, 4)
void attn_kernel(const f16* __restrict__ Qf, const f16* __restrict__ Kf,
                 const f16* __restrict__ Vtf, const f16* __restrict__ Ef,
                 float* __restrict__ out) {
    __shared__ f16 KfS[64 * 72];
    __shared__ f16 VfS[64 * 72];
    __shared__ f16 Pbuf[4][16 * 72];

    const int t = threadIdx.x, wid = t >> 6, lane = t & 63;
    const int quad = lane >> 4, col = lane & 15;
    const int l0w = blockIdx.x * 64 + wid * 16;
    const int h = blockIdx.y, bb = blockIdx.z;
    const size_t head = (size_t)(bb * NH + h) * (size_t)(L * DH);
    const f16* qf = Qf + head;
    const f16* kf = Kf + head;
    const f16* vt = Vtf + head;      // [dh][L]
    f16* Pw = Pbuf[wid];

    f16x8 qF[2], qS[2];
    {
        const int m = l0w + col;
        const int mS = min(m + 1, L - 1);   // row L never actually used
#pragma unroll
        for (int ks = 0; ks < 2; ++ks) {
            const int off = quad * 8 + ks * 32;
            qF[ks] = *(const f16x8*)(qf + (size_t)m * DH + off);
            qS[ks] = *(const f16x8*)(qf + (size_t)mS * DH + off);
        }
    }

    f16x8 kreg[2], vreg[2];
    auto loadKV = [&](int c0) {
#pragma unroll
        for (int i = 0; i < 2; ++i) {
            int idx = 256 * i + t;
            int r = idx >> 3, ch = idx & 7;
            kreg[i] = *(const f16x8*)(kf + (size_t)(c0 + r) * DH + ch * 8);
            vreg[i] = *(const f16x8*)(vt + (size_t)r * L + c0 + ch * 8);
        }
    };

    f32x4 O[4];
#pragma unroll
    for (int i = 0; i < 4; ++i) O[i] = (f32x4){0.f, 0.f, 0.f, 0.f};
    float mrow[4] = {-1e30f, -1e30f, -1e30f, -1e30f};
    float srow[4] = {0.f, 0.f, 0.f, 0.f};

    loadKV(0);
    for (int c0 = 0; c0 < L; c0 += 64) {
        __syncthreads();   // all waves done reading previous K/V tile
#pragma unroll
        for (int i = 0; i < 2; ++i) {
            int idx = 256 * i + t;
            int r = idx >> 3, ch = idx & 7;
            *(f16x8*)(KfS + r * 72 + ch * 8) = kreg[i];
            *(f16x8*)(VfS + r * 72 + ch * 8) = vreg[i];
        }
        __syncthreads();
        if (c0 + 64 < L) loadKV(c0 + 64);   // prefetch; drains behind this tile's compute

        const int d0 = c0 - l0w;

        // ---- S = Q K^T (fp16 single pass) ----
        f32x4 S[4];
#pragma unroll
        for (int ns = 0; ns < 4; ++ns) {
            S[ns] = (f32x4){0.f, 0.f, 0.f, 0.f};
#pragma unroll
            for (int ks = 0; ks < 2; ++ks) {
                f16x8 bh = *(const f16x8*)(KfS + (ns * 16 + col) * 72 + quad * 8 + ks * 32);
                S[ns] = __builtin_amdgcn_mfma_f32_16x16x32_f16(qF[ks], bh, S[ns], 0, 0, 0);
            }
        }

        // ---- Srel: G = Q . E-window^T, scatter via intra-quad shuffles ----
        const bool doA = (d0 <= 15);
        const bool doB = (d0 >= -61);
#pragma unroll 1
        for (int pass = 0; pass < 2; ++pass) {
            if ((pass == 0 && !doA) || (pass == 1 && !doB)) continue;
            const int jbase = (pass == 0) ? (d0 + L - 16) : (d0 - 17);
            f32x4 G[5];
#pragma unroll
            for (int g = 0; g < 5; ++g) {
                int er = min(max(jbase + g * 16 + col, 0), L - 1);
                G[g] = (f32x4){0.f, 0.f, 0.f, 0.f};
                const size_t eb = (size_t)er * DH + quad * 8;
#pragma unroll
                for (int ks = 0; ks < 2; ++ks) {
                    f16x8 e8 = *(const f16x8*)(Ef + eb + ks * 32);
                    G[g] = __builtin_amdgcn_mfma_f32_16x16x32_f16(
                               (pass == 0) ? qF[ks] : qS[ks], e8, G[g], 0, 0, 0);
                }
            }
#pragma unroll
            for (int reg = 0; reg < 4; ++reg) {
                const int r  = quad * 4 + reg;
                const int jj = col - r + 15;            // [0,30]
                const int src = quad * 16 + (jj & 15);  // same quad holds row r
#pragma unroll
                for (int ns = 0; ns < 4; ++ns) {
                    float v0 = __shfl(G[ns][reg], src, 64);
                    float v1 = __shfl(G[ns + 1][reg], src, 64);
                    float val = (jj < 16) ? v0 : v1;
                    const int rel = d0 + ns * 16 + col - r;
                    const bool use = (pass == 0) ? (rel <= 0) : (rel >= 2);
                    if (use) S[ns][reg] += val;
                }
            }
        }

        // ---- online softmax (rows in 16-lane groups) ----
#pragma unroll
        for (int reg = 0; reg < 4; ++reg) {
            float tm = fmaxf(fmaxf(S[0][reg], S[1][reg]), fmaxf(S[2][reg], S[3][reg]));
#pragma unroll
            for (int msk = 1; msk < 16; msk <<= 1)
                tm = fmaxf(tm, __shfl_xor(tm, msk, 16));
            const float mnew  = fmaxf(mrow[reg], tm);
            const float alpha = __expf(mrow[reg] - mnew);
            float p[4], ps = 0.f;
#pragma unroll
            for (int ns = 0; ns < 4; ++ns) { p[ns] = __expf(S[ns][reg] - mnew); ps += p[ns]; }
#pragma unroll
            for (int msk = 1; msk < 16; msk <<= 1)
                ps += __shfl_xor(ps, msk, 16);
            srow[reg] = srow[reg] * alpha + ps;
            mrow[reg] = mnew;
            const int r = quad * 4 + reg;
#pragma unroll
            for (int ns = 0; ns < 4; ++ns) {
                O[ns][reg] *= alpha;
                Pw[r * 72 + ns * 16 + col] = (f16)p[ns];
            }
        }
        // wave-private Pw write->read ordered by lgkmcnt within the wave

        // ---- O += P V ----
        f16x8 pA[2];
        pA[0] = *(const f16x8*)(Pw + col * 72 + quad * 8);
        pA[1] = *(const f16x8*)(Pw + col * 72 + 32 + quad * 8);
#pragma unroll
        for (int ns = 0; ns < 4; ++ns) {
#pragma unroll
            for (int ks = 0; ks < 2; ++ks) {
                f16x8 v8 = *(const f16x8*)(VfS + (ns * 16 + col) * 72 + quad * 8 + ks * 32);
                O[ns] = __builtin_amdgcn_mfma_f32_16x16x32_f16(pA[ks], v8, O[ns], 0, 0, 0);
            }
        }
    }

#pragma unroll
    for (int reg = 0; reg < 4; ++reg) {
        const int l = l0w + quad * 4 + reg;
        const float inv = 1.0f / (srow[reg] * 8.0f);
        float* o = out + ((size_t)bb * L + l) * D + h * DH;
#pragma unroll
        for (int ns = 0; ns < 4; ++ns)
            o[ns * 16 + col] = O[ns][reg] * inv;
    }
}

extern "C" void kernel_launch(void* const* d_in, const int* in_sizes, int n_in,
                              void* d_out, int out_size, void* d_ws, size_t ws_size,
                              hipStream_t stream) {
    const float* q  = (const float*)d_in[0];
    const float* k  = (const float*)d_in[1];
    const float* v  = (const float*)d_in[2];
    const float* Wq = (const float*)d_in[3];
    const float* Wk = (const float*)d_in[4];
    const float* Wv = (const float*)d_in[5];
    const float* E  = (const float*)d_in[6];
    float* out = (float*)d_out;

    // ws (fp16 elems): Qf | Kf | Vtf (4M each) | Wt (3x256K) | Ef (128K) = ~27 MB
    const size_t plane = (size_t)B * NH * L * DH;
    f16* Qf  = (f16*)d_ws;
    f16* Kfp = Qf + plane;
    f16* Vtf = Kfp + plane;
    f16* Wt  = Vtf + plane;
    f16* Ef  = Wt + (size_t)3 * D * D;

    ecast_kernel<<<L * DH / 1024, 256, 0, stream>>>(E, Ef);
    wtrans_kernel<<<dim3(8, 8, 3), 256, 0, stream>>>(Wq, Wk, Wv, Wt);
    proj_gemm<<<dim3(64, 24), 256, 0, stream>>>(q, k, v, Wt, Qf, Kfp, Vtf);
    attn_kernel<<<dim3(L / 64, NH, B), 256, 0, stream>>>(Qf, Kfp, Vtf, Ef, out);
}